// Round 1
// 194.403 us; speedup vs baseline: 1.2157x; 1.2157x over previous
//
#include <hip/hip_runtime.h>

constexpr int   T   = 4096;
constexpr float VTH = 1.27f;
constexpr int   K   = 32;         // time chunks per row
constexpr int   L   = T / K;      // 128 steps per chunk
constexpr int   LG  = L / 4;      // 32 float4 groups per chunk
constexpr int   WG  = 160;        // warm-up groups = 640 steps (lock fail ~e^-7.3 = 0.068%/boundary
                                  //  @ measured hazard 1.14%/step; chunks 1..5 cover prefix exactly)

// ---- h-mask LIF machine (bitwise-validated vs reference: absmax 0.0 in R5) ----
// h bit j == spike at (t-1-j). gate (carried) == spike in [t-5, t-1].
__device__ __forceinline__ bool sstep(float x, float decay, float& v, unsigned& h, bool& gate) {
    float t1 = __fmul_rn(decay, v);
    float vd = __fsub_rn(v, t1);           // unfused — matches reference rounding
    float xe = gate ? 0.0f : x;
    float vn = __fadd_rn(vd, xe);
    bool  s  = vn > VTH;
    v = s ? 0.0f : vn;
    bool g4 = (h & 15u) != 0u;
    h = (h << 1) | (s ? 1u : 0u);
    gate = s || g4;
    return s;
}

// vo, so for step t; dvo = dv[t-1] (zero iff spike in [t-6, t]).
__device__ __forceinline__ bool ostep(float x, float decay, float& v, unsigned& h, bool& gate,
                                      float& vo, float& so, float& dvo, float xprev) {
    float t1 = __fmul_rn(decay, v);
    float vd = __fsub_rn(v, t1);
    float xe = gate ? 0.0f : x;
    float vn = __fadd_rn(vd, xe);
    bool  s  = vn > VTH;
    vo = s ? VTH  : vn;
    so = s ? 1.0f : 0.0f;
    v  = s ? 0.0f : vn;
    bool z6 = s || ((h & 63u) != 0u);
    dvo = z6 ? 0.0f : xprev;
    bool g4 = (h & 15u) != 0u;
    h = (h << 1) | (s ? 1u : 0u);
    gate = s || g4;
    return s;
}

__device__ __forceinline__ void ogroup(float4 X, float decay, float& v, unsigned& h, bool& gate,
                                       float& xprev, float4& vo, float4& so,
                                       float& close, float& px, float& py, float& pz) {
    ostep(X.x, decay, v, h, gate, vo.x, so.x, close, xprev); xprev = X.x;
    ostep(X.y, decay, v, h, gate, vo.y, so.y, px,    xprev); xprev = X.y;
    ostep(X.z, decay, v, h, gate, vo.z, so.z, py,    xprev); xprev = X.z;
    ostep(X.w, decay, v, h, gate, vo.w, so.w, pz,    xprev); xprev = X.w;
}

// Quad q (groups 4q..4q+3): v/s bursts; fills D0..3 (dv of this quad) except D3.w;
// its first close completes P3.w and flushes P0..3 (dv of quad q-1). q>=1.
// Prefetch is 2 quads deep: the consumed register set is refilled with quad q+2's groups.
__device__ __forceinline__ void quad_run(int q, const float4* __restrict__ x4, int g0f,
        float decay, float& v, unsigned& h, bool& gate, float& xprev,
        float4& Xa, float4& Xb, float4& Xc, float4& Xd,
        float4& D0, float4& D1, float4& D2, float4& D3,
        float4& P0, float4& P1, float4& P2, float4& P3,
        float4* __restrict__ v4, float4* __restrict__ s4, float4* __restrict__ d4) {
    float4 V0, V1, V2, V3, S0, S1, S2, S3;
    ogroup(Xa, decay, v, h, gate, xprev, V0, S0, P3.w, D0.x, D0.y, D0.z);
    Xa = x4[g0f + (4*q + 8 < LG ? 4*q + 8 : LG - 1)];
    d4[g0f + 4*q - 4] = P0; d4[g0f + 4*q - 3] = P1;
    d4[g0f + 4*q - 2] = P2; d4[g0f + 4*q - 1] = P3;
    ogroup(Xb, decay, v, h, gate, xprev, V1, S1, D0.w, D1.x, D1.y, D1.z);
    Xb = x4[g0f + (4*q + 9 < LG ? 4*q + 9 : LG - 1)];
    ogroup(Xc, decay, v, h, gate, xprev, V2, S2, D1.w, D2.x, D2.y, D2.z);
    Xc = x4[g0f + (4*q + 10 < LG ? 4*q + 10 : LG - 1)];
    ogroup(Xd, decay, v, h, gate, xprev, V3, S3, D2.w, D3.x, D3.y, D3.z);
    Xd = x4[g0f + (4*q + 11 < LG ? 4*q + 11 : LG - 1)];
    v4[g0f + 4*q] = V0; v4[g0f + 4*q + 1] = V1; v4[g0f + 4*q + 2] = V2; v4[g0f + 4*q + 3] = V3;
    s4[g0f + 4*q] = S0; s4[g0f + 4*q + 1] = S1; s4[g0f + 4*q + 2] = S2; s4[g0f + 4*q + 3] = S3;
}

// ---------------- fused speculative chunk kernel ----------------
__global__ __launch_bounds__(64, 1)
void lif_spec(const float* __restrict__ ode, const float* __restrict__ decay_p,
              float* __restrict__ vout, float* __restrict__ sout, float* __restrict__ dvout,
              float2* __restrict__ Sst, float2* __restrict__ Est, int B) {
    const int g = blockIdx.x * 64 + threadIdx.x;
    const int b = g % B;                  // consecutive lanes = consecutive rows
    const int k = g / B;                  // wave-uniform chunk id
    const float decay = decay_p[0];

    const size_t bt = (size_t)b * T;
    const float4* __restrict__ x4 = (const float4*)(ode + bt);
    float4* __restrict__ v4 = (float4*)(vout + bt);
    float4* __restrict__ s4 = (float4*)(sout + bt);
    float4* __restrict__ d4 = (float4*)(dvout + bt);

    const int g0f = k * LG;
    const int wg  = (k == 0) ? 0 : (k * LG < WG ? k * LG : WG);   // 32/64/96/128/160
    float v = 0.0f; unsigned h = 0u; bool gate = false;
    float xprev = 0.0f;

    // ---- warm-up (state only), 16-group-deep load pipeline (~1600 cyc slack).
    // Chunks 1..5 cover the full prefix -> exact.
    if (wg > 0) {
        const float4* __restrict__ xw = x4 + (g0f - wg);
        const bool t0row = (g0f - wg == 0);
        float4 Q[16];
#pragma unroll
        for (int i = 0; i < 16; ++i) Q[i] = xw[i];
        for (int c = 0; c < wg; c += 16) {
#pragma unroll
            for (int i = 0; i < 16; ++i) {
                if (i == 0 && c == 0 && t0row) {   // t=0 spike does NOT arm the window
                    sstep(Q[0].x, decay, v, h, gate); h = 0u; gate = false;
                    sstep(Q[0].y, decay, v, h, gate);
                    sstep(Q[0].z, decay, v, h, gate);
                    sstep(Q[0].w, decay, v, h, gate);
                } else {
                    sstep(Q[i].x, decay, v, h, gate);
                    sstep(Q[i].y, decay, v, h, gate);
                    sstep(Q[i].z, decay, v, h, gate);
                    sstep(Q[i].w, decay, v, h, gate);
                }
                Q[i] = xw[c + i + 16];            // reads at most 15 groups past wg: in-row, safe
            }
        }
        Sst[k * B + b] = make_float2(v, __uint_as_float(h & 127u));
    }

    // ---- main: 8 quads, A/B register-set pipeline (2 quads = 8 groups = 2 lines deep).
    // (R5-validated dv ownership: first close of the chunk is dv[t0-1], owned by chunk k-1's lookahead)
    float xla = (k < K - 1) ? ode[bt + (size_t)(k + 1) * L] : 0.0f;
    float4 A0 = x4[g0f],     A1 = x4[g0f + 1], A2 = x4[g0f + 2], A3 = x4[g0f + 3];
    float4 B0 = x4[g0f + 4], B1 = x4[g0f + 5], B2 = x4[g0f + 6], B3 = x4[g0f + 7];
    float4 DA0, DA1, DA2, DA3, DB0, DB1, DB2, DB3;

    {   // quad 0 (consumes A-set, refills it with groups 8..11)
        float4 V0, V1, V2, V3, S0, S1, S2, S3;
        if (k == 0) {
            float dvd;
            bool s0 = ostep(A0.x, decay, v, h, gate, V0.x, S0.x, dvd, xprev); xprev = A0.x;
            h = 0u; gate = false;          // t=0 spike doesn't arm the window
            bool s1 = ostep(A0.y, decay, v, h, gate, V0.y, S0.y, DA0.x, xprev); xprev = A0.y;
            ostep(A0.z, decay, v, h, gate, V0.z, S0.z, DA0.y, xprev); xprev = A0.z;
            ostep(A0.w, decay, v, h, gate, V0.w, S0.w, DA0.z, xprev); xprev = A0.w;
            if (s0 && s1) V0.z = VTH;      // counter==2 corner: spikes at t=0 and t=1
        } else {
            float cl;
            ogroup(A0, decay, v, h, gate, xprev, V0, S0, cl, DA0.x, DA0.y, DA0.z);
        }
        A0 = x4[g0f + 8];
        ogroup(A1, decay, v, h, gate, xprev, V1, S1, DA0.w, DA1.x, DA1.y, DA1.z); A1 = x4[g0f + 9];
        ogroup(A2, decay, v, h, gate, xprev, V2, S2, DA1.w, DA2.x, DA2.y, DA2.z); A2 = x4[g0f + 10];
        ogroup(A3, decay, v, h, gate, xprev, V3, S3, DA2.w, DA3.x, DA3.y, DA3.z); A3 = x4[g0f + 11];
        v4[g0f] = V0; v4[g0f + 1] = V1; v4[g0f + 2] = V2; v4[g0f + 3] = V3;
        s4[g0f] = S0; s4[g0f + 1] = S1; s4[g0f + 2] = S2; s4[g0f + 3] = S3;
    }

#define MQ(q, Xs, Dn, Pn) quad_run(q, x4, g0f, decay, v, h, gate, xprev, \
        Xs##0, Xs##1, Xs##2, Xs##3, Dn##0, Dn##1, Dn##2, Dn##3, \
        Pn##0, Pn##1, Pn##2, Pn##3, v4, s4, d4);
    MQ(1, B, DB, DA) MQ(2, A, DA, DB) MQ(3, B, DB, DA) MQ(4, A, DA, DB)
    MQ(5, B, DB, DA) MQ(6, A, DA, DB) MQ(7, B, DB, DA)
#undef MQ

    Est[k * B + b] = make_float2(v, __uint_as_float(h & 127u));   // exit, pre-lookahead

    if (k < K - 1) {                       // lookahead closes dv[t0+L-1]
        float vo_, so_;
        ostep(xla, decay, v, h, gate, vo_, so_, DB3.w, xprev);
    } else {
        DB3.w = ((h & 63u) != 0u) ? 0.0f : xprev;   // dv[T-1]
    }
    d4[g0f + LG - 4] = DB0; d4[g0f + LG - 3] = DB1;
    d4[g0f + LG - 2] = DB2; d4[g0f + LG - 1] = DB3;
}

// ---------------- verify + rare chunk-granular repair (exact by induction) ----------------
__global__ __launch_bounds__(64, 1)
void lif_fix(const float* __restrict__ ode, const float* __restrict__ decay_p,
             float* __restrict__ vout, float* __restrict__ sout, float* __restrict__ dvout,
             const float2* __restrict__ Sst, const float2* __restrict__ Est, int B) {
    const int b = blockIdx.x * 64 + threadIdx.x;
    const float decay = decay_p[0];

    float2 E = Est[b];                     // chunk 0 exit — exact
    for (int k = 1; k < K; ++k) {
        float2 S = Sst[k * B + b];
        bool match = (S.x == E.x) && (__float_as_uint(S.y) == __float_as_uint(E.y));
        if (match) { E = Est[k * B + b]; continue; }

        // rerun chunk k from exact entry E, rewriting its outputs (4-group-deep load pipeline)
        const size_t bt = (size_t)b * T;
        const float4* __restrict__ x4 = (const float4*)(ode + bt);
        float4* __restrict__ v4 = (float4*)(vout + bt);
        float4* __restrict__ s4 = (float4*)(sout + bt);
        float4* __restrict__ d4 = (float4*)(dvout + bt);
        const int g0f = k * LG;

        float v = E.x; unsigned h = __float_as_uint(E.y);
        bool gate = (h & 31u) != 0u;
        float xprev = 0.0f;
        float4 pend;

        float4 Q0 = x4[g0f], Q1 = x4[g0f + 1], Q2 = x4[g0f + 2], Q3 = x4[g0f + 3];
        {   // group 0: close (dv[t0-1]) owned by chunk k-1's (exact) lookahead
            float4 vo, so; float cl;
            ogroup(Q0, decay, v, h, gate, xprev, vo, so, cl, pend.x, pend.y, pend.z);
            v4[g0f] = vo; s4[g0f] = so;
            Q0 = x4[g0f + 4];
        }
#define FPROC(cc, Q) { float4 vo, so; float px, py, pz; \
            ogroup(Q, decay, v, h, gate, xprev, vo, so, pend.w, px, py, pz); \
            d4[g0f + (cc) - 1] = pend; \
            pend.x = px; pend.y = py; pend.z = pz; \
            v4[g0f + (cc)] = vo; s4[g0f + (cc)] = so; }
        FPROC(1, Q1) Q1 = x4[g0f + 5];
        FPROC(2, Q2) Q2 = x4[g0f + 6];
        FPROC(3, Q3) Q3 = x4[g0f + 7];
        for (int c0 = 4; c0 < LG; c0 += 4) {
            FPROC(c0,     Q0) Q0 = x4[g0f + (c0 + 4 < LG ? c0 + 4 : LG - 1)];
            FPROC(c0 + 1, Q1) Q1 = x4[g0f + (c0 + 5 < LG ? c0 + 5 : LG - 1)];
            FPROC(c0 + 2, Q2) Q2 = x4[g0f + (c0 + 6 < LG ? c0 + 6 : LG - 1)];
            FPROC(c0 + 3, Q3) Q3 = x4[g0f + (c0 + 7 < LG ? c0 + 7 : LG - 1)];
        }
#undef FPROC
        E = make_float2(v, __uint_as_float(h & 127u));   // corrected exit
        if (k < K - 1) {
            float xla = ode[bt + (size_t)(k + 1) * L];
            float vo_, so_;
            ostep(xla, decay, v, h, gate, vo_, so_, pend.w, xprev);
        } else {
            pend.w = ((h & 63u) != 0u) ? 0.0f : xprev;
        }
        d4[g0f + LG - 1] = pend;
    }
}

extern "C" void kernel_launch(void* const* d_in, const int* in_sizes, int n_in,
                              void* d_out, int out_size, void* d_ws, size_t ws_size,
                              hipStream_t stream) {
    const float* ode   = (const float*)d_in[0];
    const float* decay = (const float*)d_in[1];
    float* out = (float*)d_out;

    const int BT = in_sizes[0];            // B*T
    const int B  = BT / T;                 // 2048

    float* vout  = out;
    float* sout  = out + (size_t)BT;
    float* dvout = out + 2 * (size_t)BT;

    float2* Sst = (float2*)d_ws;           // [K][B]
    float2* Est = Sst + (size_t)K * B;     // [K][B]  (1 MB total)

    lif_spec<<<dim3((B * K) / 64), dim3(64), 0, stream>>>(ode, decay, vout, sout, dvout,
                                                          Sst, Est, B);
    lif_fix<<<dim3(B / 64), dim3(64), 0, stream>>>(ode, decay, vout, sout, dvout,
                                                   Sst, Est, B);
}

// Round 2
// 180.131 us; speedup vs baseline: 1.3120x; 1.0792x over previous
//
#include <hip/hip_runtime.h>

constexpr int   T   = 4096;
constexpr float VTH = 1.27f;
constexpr int   K   = 32;         // time chunks per row
constexpr int   L   = T / K;      // 128 steps per chunk
constexpr int   LG  = L / 4;      // 32 float4 groups per chunk
constexpr int   WG  = 160;        // warm-up groups = 640 steps (lock fail ~e^-7.3 = 0.068%/boundary)

// ---- h-mask LIF machine (bitwise-validated vs reference: absmax 0.0) ----
// h bit j == spike at (t-1-j). gate (carried) == spike in [t-5, t-1].
__device__ __forceinline__ bool sstep(float x, float decay, float& v, unsigned& h, bool& gate) {
    float t1 = __fmul_rn(decay, v);
    float vd = __fsub_rn(v, t1);           // unfused — matches reference rounding
    float xe = gate ? 0.0f : x;
    float vn = __fadd_rn(vd, xe);
    bool  s  = vn > VTH;
    v = s ? 0.0f : vn;
    bool g4 = (h & 15u) != 0u;
    h = (h << 1) | (s ? 1u : 0u);
    gate = s || g4;
    return s;
}

// vo, so for step t; dvo = dv[t-1] (zero iff spike in [t-6, t]).
__device__ __forceinline__ bool ostep(float x, float decay, float& v, unsigned& h, bool& gate,
                                      float& vo, float& so, float& dvo, float xprev) {
    float t1 = __fmul_rn(decay, v);
    float vd = __fsub_rn(v, t1);
    float xe = gate ? 0.0f : x;
    float vn = __fadd_rn(vd, xe);
    bool  s  = vn > VTH;
    vo = s ? VTH  : vn;
    so = s ? 1.0f : 0.0f;
    v  = s ? 0.0f : vn;
    bool z6 = s || ((h & 63u) != 0u);
    dvo = z6 ? 0.0f : xprev;
    bool g4 = (h & 15u) != 0u;
    h = (h << 1) | (s ? 1u : 0u);
    gate = s || g4;
    return s;
}

__device__ __forceinline__ void ogroup(float4 X, float decay, float& v, unsigned& h, bool& gate,
                                       float& xprev, float4& vo, float4& so,
                                       float& close, float& px, float& py, float& pz) {
    ostep(X.x, decay, v, h, gate, vo.x, so.x, close, xprev); xprev = X.x;
    ostep(X.y, decay, v, h, gate, vo.y, so.y, px,    xprev); xprev = X.y;
    ostep(X.z, decay, v, h, gate, vo.z, so.z, py,    xprev); xprev = X.z;
    ostep(X.w, decay, v, h, gate, vo.w, so.w, pz,    xprev); xprev = X.w;
}

// ---------------- fused speculative chunk kernel, LDS-transposed stores ----------------
// Output path: per lane -> LDS tile (row stride 5 float4: 5*lane mod 8 is a permutation =>
// conflict-free writes), per quad: transpose-read (4 lanes/row) -> full-64B-line global stores.
// dv lags one quad (its last element closes at next quad's first step) -> 2-slot ring.
__global__ __launch_bounds__(64, 1)
void lif_spec(const float* __restrict__ ode, const float* __restrict__ decay_p,
              float* __restrict__ vout, float* __restrict__ sout, float* __restrict__ dvout,
              float2* __restrict__ Sst, float2* __restrict__ Est, int B) {
    __shared__ float4 tv[64 * 5];          // v, one 16-t quad slot
    __shared__ float4 ts[64 * 5];          // s
    __shared__ float4 td[2][64 * 5];       // dv, 2-slot ring (lags one quad)

    const int tid = threadIdx.x;
    const int gg  = blockIdx.x * 64;
    const int rb  = gg % B;                // row block base; wave = 64 consecutive rows
    const int k   = gg / B;                // wave-uniform chunk id
    const int b   = rb + tid;
    const float decay = decay_p[0];

    const size_t bt = (size_t)b * T;
    const float4* __restrict__ x4 = (const float4*)(ode + bt);

    const int g0f = k * LG;
    const int wg  = (k == 0) ? 0 : (k * LG < WG ? k * LG : WG);
    float v = 0.0f; unsigned h = 0u; bool gate = false;
    float xprev = 0.0f;

    // ---- warm-up (state only), 16-group-deep load pipeline. Chunks 1..5 cover prefix exactly.
    if (wg > 0) {
        const float4* __restrict__ xw = x4 + (g0f - wg);
        const bool t0row = (g0f - wg == 0);
        float4 Q[16];
#pragma unroll
        for (int i = 0; i < 16; ++i) Q[i] = xw[i];
        for (int c = 0; c < wg; c += 16) {
#pragma unroll
            for (int i = 0; i < 16; ++i) {
                if (i == 0 && c == 0 && t0row) {   // t=0 spike does NOT arm the window
                    sstep(Q[0].x, decay, v, h, gate); h = 0u; gate = false;
                    sstep(Q[0].y, decay, v, h, gate);
                    sstep(Q[0].z, decay, v, h, gate);
                    sstep(Q[0].w, decay, v, h, gate);
                } else {
                    sstep(Q[i].x, decay, v, h, gate);
                    sstep(Q[i].y, decay, v, h, gate);
                    sstep(Q[i].z, decay, v, h, gate);
                    sstep(Q[i].w, decay, v, h, gate);
                }
                Q[i] = xw[c + i + 16];            // reads at most 15 groups past wg: in-row, safe
            }
        }
        Sst[k * B + b] = make_float2(v, __uint_as_float(h & 127u));
    }

    // transpose-store addressing: instr j covers rows rb+16j+(tid>>2), t-part (tid&3)*4
    int rowoff0 = (rb + (tid >> 2)) * T + k * L + (tid & 3) * 4;
    const int wbase = tid * 5;
    const int rbase = (tid >> 2) * 5 + (tid & 3);

    // ---- main: 8 quads, A/B input register pipeline (2 quads deep), LDS-staged outputs
    float xla = (k < K - 1) ? ode[bt + (size_t)(k + 1) * L] : 0.0f;
    float4 A0 = x4[g0f],     A1 = x4[g0f + 1], A2 = x4[g0f + 2], A3 = x4[g0f + 3];
    float4 B0 = x4[g0f + 4], B1 = x4[g0f + 5], B2 = x4[g0f + 6], B3 = x4[g0f + 7];
    float4 Pd;                             // rolling dv group (xyz pending, w = close)

// group gidx (compile-time): compute, stage dv col gidx-1, stage v/s col gidx&3
#define OG(X, gidx) { float4 V_, S_; float cl_, p0_, p1_, p2_; \
        ogroup(X, decay, v, h, gate, xprev, V_, S_, cl_, p0_, p1_, p2_); \
        if ((gidx) > 0) { Pd.w = cl_; td[(((gidx)-1) >> 2) & 1][wbase + (((gidx)-1) & 3)] = Pd; } \
        Pd.x = p0_; Pd.y = p1_; Pd.z = p2_; \
        tv[wbase + ((gidx) & 3)] = V_; ts[wbase + ((gidx) & 3)] = S_; }

// end of quad q: flush v/s (quad q) and dv (quad q-1, complete since quad q's first close)
#define FLUSH(q) { __syncthreads(); \
        float4 Vv0 = tv[rbase], Vv1 = tv[rbase + 80], Vv2 = tv[rbase + 160], Vv3 = tv[rbase + 240]; \
        float4 Ss0 = ts[rbase], Ss1 = ts[rbase + 80], Ss2 = ts[rbase + 160], Ss3 = ts[rbase + 240]; \
        *(float4*)(vout + rowoff0 + (q)*16)            = Vv0; \
        *(float4*)(vout + rowoff0 + 16*T + (q)*16)     = Vv1; \
        *(float4*)(vout + rowoff0 + 32*T + (q)*16)     = Vv2; \
        *(float4*)(vout + rowoff0 + 48*T + (q)*16)     = Vv3; \
        *(float4*)(sout + rowoff0 + (q)*16)            = Ss0; \
        *(float4*)(sout + rowoff0 + 16*T + (q)*16)     = Ss1; \
        *(float4*)(sout + rowoff0 + 32*T + (q)*16)     = Ss2; \
        *(float4*)(sout + rowoff0 + 48*T + (q)*16)     = Ss3; \
        if ((q) >= 1) { \
            float4 Dd0 = td[((q)-1)&1][rbase],       Dd1 = td[((q)-1)&1][rbase + 80]; \
            float4 Dd2 = td[((q)-1)&1][rbase + 160], Dd3 = td[((q)-1)&1][rbase + 240]; \
            *(float4*)(dvout + rowoff0 + ((q)-1)*16)        = Dd0; \
            *(float4*)(dvout + rowoff0 + 16*T + ((q)-1)*16) = Dd1; \
            *(float4*)(dvout + rowoff0 + 32*T + ((q)-1)*16) = Dd2; \
            *(float4*)(dvout + rowoff0 + 48*T + ((q)-1)*16) = Dd3; } }

    {   // quad 0
        if (k == 0) {
            float4 V_, S_; float dvd;
            bool s0 = ostep(A0.x, decay, v, h, gate, V_.x, S_.x, dvd, xprev); xprev = A0.x;
            h = 0u; gate = false;          // t=0 spike doesn't arm the window
            bool s1 = ostep(A0.y, decay, v, h, gate, V_.y, S_.y, Pd.x, xprev); xprev = A0.y;
            ostep(A0.z, decay, v, h, gate, V_.z, S_.z, Pd.y, xprev); xprev = A0.z;
            ostep(A0.w, decay, v, h, gate, V_.w, S_.w, Pd.z, xprev); xprev = A0.w;
            if (s0 && s1) V_.z = VTH;      // counter==2 corner: spikes at t=0 and t=1
            tv[wbase] = V_; ts[wbase] = S_;
        } else {
            float4 V_, S_; float cl_;      // close = dv[t0-1]: owned by chunk k-1's lookahead
            ogroup(A0, decay, v, h, gate, xprev, V_, S_, cl_, Pd.x, Pd.y, Pd.z);
            tv[wbase] = V_; ts[wbase] = S_;
        }
        A0 = x4[g0f + 8];
        OG(A1, 1) A1 = x4[g0f + 9];
        OG(A2, 2) A2 = x4[g0f + 10];
        OG(A3, 3) A3 = x4[g0f + 11];
        FLUSH(0)
    }

#define MQ(q, Xs) \
        OG(Xs##0, 4*(q)+0) Xs##0 = x4[g0f + (4*(q)+8  < LG ? 4*(q)+8  : LG-1)]; \
        OG(Xs##1, 4*(q)+1) Xs##1 = x4[g0f + (4*(q)+9  < LG ? 4*(q)+9  : LG-1)]; \
        OG(Xs##2, 4*(q)+2) Xs##2 = x4[g0f + (4*(q)+10 < LG ? 4*(q)+10 : LG-1)]; \
        OG(Xs##3, 4*(q)+3) Xs##3 = x4[g0f + (4*(q)+11 < LG ? 4*(q)+11 : LG-1)]; \
        FLUSH(q)
    MQ(1, B) MQ(2, A) MQ(3, B) MQ(4, A) MQ(5, B) MQ(6, A) MQ(7, B)
#undef MQ
#undef OG

    Est[k * B + b] = make_float2(v, __uint_as_float(h & 127u));   // exit, pre-lookahead

    if (k < K - 1) {                       // lookahead closes dv[t0+L-1]
        float vo_, so_;
        ostep(xla, decay, v, h, gate, vo_, so_, Pd.w, xprev);
    } else {
        Pd.w = ((h & 63u) != 0u) ? 0.0f : xprev;   // dv[T-1]
    }
    td[1][wbase + 3] = Pd;                 // col 31: slot 1, local col 3
    __syncthreads();
    {   // flush dv quad 7 (slot 1)
        float4 Dd0 = td[1][rbase],       Dd1 = td[1][rbase + 80];
        float4 Dd2 = td[1][rbase + 160], Dd3 = td[1][rbase + 240];
        *(float4*)(dvout + rowoff0 + 7*16)        = Dd0;
        *(float4*)(dvout + rowoff0 + 16*T + 7*16) = Dd1;
        *(float4*)(dvout + rowoff0 + 32*T + 7*16) = Dd2;
        *(float4*)(dvout + rowoff0 + 48*T + 7*16) = Dd3;
    }
#undef FLUSH
}

// ---------------- verify + rare chunk-granular repair (exact by induction) ----------------
__global__ __launch_bounds__(64, 1)
void lif_fix(const float* __restrict__ ode, const float* __restrict__ decay_p,
             float* __restrict__ vout, float* __restrict__ sout, float* __restrict__ dvout,
             const float2* __restrict__ Sst, const float2* __restrict__ Est, int B) {
    const int b = blockIdx.x * 64 + threadIdx.x;
    const float decay = decay_p[0];

    float2 E  = Est[b];                    // chunk 0 exit — exact
    float2 S1 = Sst[B + b];
    float2 E1 = Est[B + b];
    for (int k = 1; k < K; ++k) {
        float2 S = S1, Ek = E1;
        if (k + 1 < K) { S1 = Sst[(k + 1) * B + b]; E1 = Est[(k + 1) * B + b]; }
        bool match = (S.x == E.x) && (__float_as_uint(S.y) == __float_as_uint(E.y));
        if (match) { E = Ek; continue; }

        // rerun chunk k from exact entry E, rewriting its outputs (4-group-deep load pipeline)
        const size_t bt = (size_t)b * T;
        const float4* __restrict__ x4 = (const float4*)(ode + bt);
        float4* __restrict__ v4 = (float4*)(vout + bt);
        float4* __restrict__ s4 = (float4*)(sout + bt);
        float4* __restrict__ d4 = (float4*)(dvout + bt);
        const int g0f = k * LG;

        float v = E.x; unsigned h = __float_as_uint(E.y);
        bool gate = (h & 31u) != 0u;
        float xprev = 0.0f;
        float4 pend;

        float4 Q0 = x4[g0f], Q1 = x4[g0f + 1], Q2 = x4[g0f + 2], Q3 = x4[g0f + 3];
        {   // group 0: close (dv[t0-1]) owned by chunk k-1's (exact) lookahead
            float4 vo, so; float cl;
            ogroup(Q0, decay, v, h, gate, xprev, vo, so, cl, pend.x, pend.y, pend.z);
            v4[g0f] = vo; s4[g0f] = so;
            Q0 = x4[g0f + 4];
        }
#define FPROC(cc, Q) { float4 vo, so; float px, py, pz; \
            ogroup(Q, decay, v, h, gate, xprev, vo, so, pend.w, px, py, pz); \
            d4[g0f + (cc) - 1] = pend; \
            pend.x = px; pend.y = py; pend.z = pz; \
            v4[g0f + (cc)] = vo; s4[g0f + (cc)] = so; }
        FPROC(1, Q1) Q1 = x4[g0f + 5];
        FPROC(2, Q2) Q2 = x4[g0f + 6];
        FPROC(3, Q3) Q3 = x4[g0f + 7];
        for (int c0 = 4; c0 < LG; c0 += 4) {
            FPROC(c0,     Q0) Q0 = x4[g0f + (c0 + 4 < LG ? c0 + 4 : LG - 1)];
            FPROC(c0 + 1, Q1) Q1 = x4[g0f + (c0 + 5 < LG ? c0 + 5 : LG - 1)];
            FPROC(c0 + 2, Q2) Q2 = x4[g0f + (c0 + 6 < LG ? c0 + 6 : LG - 1)];
            FPROC(c0 + 3, Q3) Q3 = x4[g0f + (c0 + 7 < LG ? c0 + 7 : LG - 1)];
        }
#undef FPROC
        E = make_float2(v, __uint_as_float(h & 127u));   // corrected exit
        if (k < K - 1) {
            float xla = ode[bt + (size_t)(k + 1) * L];
            float vo_, so_;
            ostep(xla, decay, v, h, gate, vo_, so_, pend.w, xprev);
        } else {
            pend.w = ((h & 63u) != 0u) ? 0.0f : xprev;
        }
        d4[g0f + LG - 1] = pend;
    }
}

extern "C" void kernel_launch(void* const* d_in, const int* in_sizes, int n_in,
                              void* d_out, int out_size, void* d_ws, size_t ws_size,
                              hipStream_t stream) {
    const float* ode   = (const float*)d_in[0];
    const float* decay = (const float*)d_in[1];
    float* out = (float*)d_out;

    const int BT = in_sizes[0];            // B*T
    const int B  = BT / T;                 // 2048

    float* vout  = out;
    float* sout  = out + (size_t)BT;
    float* dvout = out + 2 * (size_t)BT;

    float2* Sst = (float2*)d_ws;           // [K][B]
    float2* Est = Sst + (size_t)K * B;     // [K][B]  (1 MB total)

    lif_spec<<<dim3((B * K) / 64), dim3(64), 0, stream>>>(ode, decay, vout, sout, dvout,
                                                          Sst, Est, B);
    lif_fix<<<dim3(B / 64), dim3(64), 0, stream>>>(ode, decay, vout, sout, dvout,
                                                   Sst, Est, B);
}